// Round 11
// baseline (176.964 us; speedup 1.0000x reference)
//
#include <hip/hip_runtime.h>
#include <hip/hip_bf16.h>

// ---------------------------------------------------------------------------
// NattenBlock fused mega-kernel v2. 2048 pixels (2x32x32), d_model 768,
// 7x7 NATTEN, GQA 12q/4kv, D=64.
// Round 11 (= R10 + fence-spelling fix): persistent kernel (384 blocks) with
// corrected grid barrier:
//   - relaxed-load spin (R5 bug: acquire-load per poll = L2 invalidate storm)
//   - 8 sharded arrival counters, 64B apart (R5 bug: 384 RMWs to one line)
//   - one release fence (arrival) + one acquire fence (exit) per block,
//     via __builtin_amdgcn_fence(..., "agent")  [__hip_atomic_fence doesn't exist]
// Phase bodies = R9's proven kernels: P0 convert, P1 flipped qkv GEMM
// (64x64/BK=128 glds), P2 staging-free natten MFMA, P3 flipped out GEMM.
// Co-residency: 32KB LDS + launch_bounds(256,2) -> >=2 blocks/CU, 512>=384.
// ---------------------------------------------------------------------------

typedef __attribute__((ext_vector_type(8))) __bf16 bf16x8;
typedef __attribute__((ext_vector_type(4))) float floatx4;
typedef unsigned short u16;

#define GRID 384

__device__ inline u16 f2bf(float f) {
    union { float f; unsigned u; } v; v.f = f;
    return (u16)((v.u + 0x7fff + ((v.u >> 16) & 1)) >> 16);   // RNE
}

__device__ inline void gl_lds16(const void* g, void* l) {
    __builtin_amdgcn_global_load_lds(
        (const __attribute__((address_space(1))) void*)g,
        (__attribute__((address_space(3))) void*)l, 16, 0, 0);
}

struct SmemG { u16 As[4 * 2048]; u16 Bs[4 * 2048]; };   // 32 KB
struct SmemN { u16 Pw[4 * 512]; };                      //  4 KB
union Smem { SmemG g; SmemN n; };

// Grid barrier v2. cnt = 8 shard counters spaced 16 uints (64 B) apart,
// monotonic across phases; target = phase * GRID on the shard sum.
__device__ inline void gridbar(unsigned* cnt, int bid, unsigned phase) {
    __syncthreads();
    if (threadIdx.x == 0) {
        // one release fence: publish this block's prior writes device-wide
        __builtin_amdgcn_fence(__ATOMIC_RELEASE, "agent");
        __hip_atomic_fetch_add(&cnt[(bid & 7) * 16], 1u,
                               __ATOMIC_RELAXED, __HIP_MEMORY_SCOPE_AGENT);
        const unsigned target = phase * GRID;
        for (;;) {
            unsigned s = 0;
            #pragma unroll
            for (int i = 0; i < 8; i++)
                s += __hip_atomic_load(&cnt[i * 16], __ATOMIC_RELAXED,
                                       __HIP_MEMORY_SCOPE_AGENT);
            if (s >= target) break;
            __builtin_amdgcn_s_sleep(4);
        }
        // one acquire fence: make peer blocks' writes visible here
        __builtin_amdgcn_fence(__ATOMIC_ACQUIRE, "agent");
    }
    __syncthreads();
}

// Flipped GEMM-NT tile: C'[dim,pix] = A[dim,K] @ B[pix,K]^T, bf16 in, fp32
// acc. 64x64 tile, BK=128 (4 kc of [64][32] m97 layout), glds staging.
// MODE 1 (qkv): dim<1024 -> qkvb[pix*1024+dim] (ushort4); dim>=1024 ->
//   vT[(dim-1024)*2048+pix]. MODE 0 (out): out[pix*768+dim] float4.
template<int MODE>
__device__ __forceinline__ void gemm_tile(
    const u16* __restrict__ A, const u16* __restrict__ B,
    float* __restrict__ out, u16* __restrict__ Cq, u16* __restrict__ vT,
    int bm, int bn, int K, SmemG& sm)
{
    const int tid = threadIdx.x;
    const int lane = tid & 63;
    const int wave = tid >> 6;
    const int qr = (wave >> 1) * 32;
    const int qc = (wave & 1) * 32;

    floatx4 acc[2][2] = {};

    const u16* Xsrc = (wave < 2) ? A : B;
    const int   bx  = (wave < 2) ? bm : bn;
    u16* Xlds       = (wave < 2) ? sm.As : sm.Bs;
    const int half  = wave & 1;
    const int l2 = lane >> 2;
    const int l3 = (lane & 3) * 8;
    int gofs[8], lofs[8];
    #pragma unroll
    for (int cc = 0; cc < 8; cc++) {
        int c = half * 8 + cc, kc = c & 3, rg = c >> 2;
        gofs[cc] = (bx + rg * 16 + l2) * K + kc * 32 + l3;
        lofs[cc] = kc * 2048 + rg * 512;
    }

    const int fr = lane & 15;
    const int fk = (lane >> 4) * 8;

    for (int k0 = 0; k0 < K; k0 += 128) {
        #pragma unroll
        for (int cc = 0; cc < 8; cc++)
            gl_lds16(Xsrc + gofs[cc] + k0, Xlds + lofs[cc]);
        __syncthreads();
        #pragma unroll
        for (int kc = 0; kc < 4; kc++) {
            bf16x8 af0 = *(const bf16x8*)&sm.As[kc * 2048 + (qr +      fr) * 32 + fk];
            bf16x8 af1 = *(const bf16x8*)&sm.As[kc * 2048 + (qr + 16 + fr) * 32 + fk];
            bf16x8 bf0 = *(const bf16x8*)&sm.Bs[kc * 2048 + (qc +      fr) * 32 + fk];
            bf16x8 bf1 = *(const bf16x8*)&sm.Bs[kc * 2048 + (qc + 16 + fr) * 32 + fk];
            acc[0][0] = __builtin_amdgcn_mfma_f32_16x16x32_bf16(af0, bf0, acc[0][0], 0, 0, 0);
            acc[0][1] = __builtin_amdgcn_mfma_f32_16x16x32_bf16(af0, bf1, acc[0][1], 0, 0, 0);
            acc[1][0] = __builtin_amdgcn_mfma_f32_16x16x32_bf16(af1, bf0, acc[1][0], 0, 0, 0);
            acc[1][1] = __builtin_amdgcn_mfma_f32_16x16x32_bf16(af1, bf1, acc[1][1], 0, 0, 0);
        }
        __syncthreads();
    }

    // C/D layout: col(=pixel) = lane&15, row(=dim) = (lane>>4)*4 + r.
    const int cr = (lane >> 4) * 4;
    const int ccol = lane & 15;
    #pragma unroll
    for (int i = 0; i < 2; i++) {
        #pragma unroll
        for (int j = 0; j < 2; j++) {
            const int row0 = bm + qr + i * 16 + cr;       // dim
            const int col  = bn + qc + j * 16 + ccol;     // pixel
            if (MODE == 0) {
                float4 w = {acc[i][j][0], acc[i][j][1], acc[i][j][2], acc[i][j][3]};
                *(float4*)&out[(size_t)col * 768 + row0] = w;
            } else {
                if (row0 < 1024) {
                    ushort4 w;
                    w.x = f2bf(acc[i][j][0]); w.y = f2bf(acc[i][j][1]);
                    w.z = f2bf(acc[i][j][2]); w.w = f2bf(acc[i][j][3]);
                    *(ushort4*)&Cq[(size_t)col * 1024 + row0] = w;
                } else {
                    #pragma unroll
                    for (int r = 0; r < 4; r++)
                        vT[(size_t)(row0 + r - 1024) * 2048 + col] = f2bf(acc[i][j][r]);
                }
            }
        }
    }
}

// NATTEN 7x7 MFMA, staging-free (R9). Block = (q-head h, 8x8 pixel tile).
__device__ __forceinline__ void natten_tile(
    const u16* __restrict__ qkv, const u16* __restrict__ vT,
    u16* __restrict__ o, int h, int tb, SmemN& sm)
{
    const int g  = h & 3;
    const int batch = tb >> 4;
    const int ti = ((tb >> 2) & 3) * 8;
    const int tj = (tb & 3) * 8;
    const int wu_i = min(max(ti - 3, 0), 18);
    const int oj   = min(max(tj - 3, 0) & ~3, 16);
    const int lane = threadIdx.x & 63, wave = threadIdx.x >> 6;
    const int pixbase = batch << 10;

    const int fr = lane & 15;
    const int fk = (lane >> 4) * 8;

    bf16x8 aq0, aq1;
    {
        int qq = wave * 16 + fr;
        int pixq = pixbase + (ti + (qq >> 3)) * 32 + tj + (qq & 7);
        const u16* qp = &qkv[(size_t)pixq * 1024 + h * 64];
        aq0 = *(const bf16x8*)(qp + fk);
        aq1 = *(const bf16x8*)(qp + 32 + fk);
    }

    bool colok[4]; int tlo[4], thi[4];
    #pragma unroll
    for (int r = 0; r < 4; r++) {
        int qq = wave * 16 + (lane >> 4) * 4 + r;
        int qi = ti + (qq >> 3), qj = tj + (qq & 7);
        int si = min(max(qi - 3, 0), 25);
        int sj = min(max(qj - 3, 0), 25);
        colok[r] = (oj + fr >= sj) && (oj + fr <= sj + 6);
        tlo[r] = si - wu_i; thi[r] = tlo[r] + 6;
    }

    float s[14][4];
    float mx[4] = {-1e30f, -1e30f, -1e30f, -1e30f};
    #pragma unroll
    for (int t = 0; t < 14; t++) {
        int kp = pixbase + (wu_i + t) * 32 + oj + fr;
        const u16* krow = &qkv[(size_t)kp * 1024 + 768 + g * 64];
        bf16x8 bk0 = *(const bf16x8*)(krow + fk);
        bf16x8 bk1 = *(const bf16x8*)(krow + 32 + fk);
        floatx4 a4 = {};
        a4 = __builtin_amdgcn_mfma_f32_16x16x32_bf16(aq0, bk0, a4, 0, 0, 0);
        a4 = __builtin_amdgcn_mfma_f32_16x16x32_bf16(aq1, bk1, a4, 0, 0, 0);
        #pragma unroll
        for (int r = 0; r < 4; r++) {
            bool v = colok[r] && (t >= tlo[r]) && (t <= thi[r]);
            s[t][r] = v ? a4[r] * 0.125f : -1e30f;
            mx[r] = fmaxf(mx[r], s[t][r]);
        }
    }
    #pragma unroll
    for (int r = 0; r < 4; r++) {
        mx[r] = fmaxf(mx[r], __shfl_xor(mx[r], 1));
        mx[r] = fmaxf(mx[r], __shfl_xor(mx[r], 2));
        mx[r] = fmaxf(mx[r], __shfl_xor(mx[r], 4));
        mx[r] = fmaxf(mx[r], __shfl_xor(mx[r], 8));
    }
    float l[4] = {0.f, 0.f, 0.f, 0.f};
    #pragma unroll
    for (int t = 0; t < 14; t++)
        #pragma unroll
        for (int r = 0; r < 4; r++) {
            float p = __expf(s[t][r] - mx[r]);
            s[t][r] = p; l[r] += p;
        }
    #pragma unroll
    for (int r = 0; r < 4; r++) {
        l[r] += __shfl_xor(l[r], 1);
        l[r] += __shfl_xor(l[r], 2);
        l[r] += __shfl_xor(l[r], 4);
        l[r] += __shfl_xor(l[r], 8);
    }
    float rinv[4];
    #pragma unroll
    for (int r = 0; r < 4; r++) rinv[r] = 1.0f / l[r];

    u16* pw = &sm.Pw[wave * 512];
    floatx4 oacc[4] = {};
    const int vrow = (fk >= 16) ? 1 : 0;
    const int vcol = oj + (fk & 8);
    #pragma unroll
    for (int kc = 0; kc < 7; kc++) {
        #pragma unroll
        for (int tt = 0; tt < 2; tt++) {
            int t = kc * 2 + tt;
            #pragma unroll
            for (int r = 0; r < 4; r++)
                pw[((lane >> 4) * 4 + r) * 32 + tt * 16 + fr] =
                    f2bf(s[t][r] * rinv[r]);
        }
        bf16x8 bp = *(const bf16x8*)&pw[fr * 32 + fk];
        const int vpix = pixbase + (wu_i + kc * 2 + vrow) * 32 + vcol;
        #pragma unroll
        for (int u = 0; u < 4; u++) {
            const u16* vp = &vT[(size_t)(g * 64 + u * 16 + fr) * 2048 + vpix];
            union { ushort4 q[2]; bf16x8 v; } av;
            av.q[0] = *(const ushort4*)vp;
            av.q[1] = *(const ushort4*)(vp + 4);
            oacc[u] = __builtin_amdgcn_mfma_f32_16x16x32_bf16(av.v, bp, oacc[u], 0, 0, 0);
        }
    }

    {
        int qq = wave * 16 + fr;
        int pixq = pixbase + (ti + (qq >> 3)) * 32 + tj + (qq & 7);
        u16* op = &o[(size_t)pixq * 768 + h * 64];
        #pragma unroll
        for (int u = 0; u < 4; u++) {
            ushort4 w;
            w.x = f2bf(oacc[u][0]); w.y = f2bf(oacc[u][1]);
            w.z = f2bf(oacc[u][2]); w.w = f2bf(oacc[u][3]);
            *(ushort4*)(op + u * 16 + (lane >> 4) * 4) = w;
        }
    }
}

__global__ __launch_bounds__(256, 2) void mega_kernel(
    const float* __restrict__ x, const float* __restrict__ w1,
    const float* __restrict__ w2,
    u16* __restrict__ xb, u16* __restrict__ w1b, u16* __restrict__ w2b,
    u16* __restrict__ qkvb, u16* __restrict__ vTb, u16* __restrict__ ob,
    float* __restrict__ out, unsigned* __restrict__ bar)
{
    __shared__ Smem sm;
    const int bid = blockIdx.x;
    const int tid = threadIdx.x;

    // ---- P0: fp32 -> bf16 convert (786432 float4, 8/thread).
    {
        int base = bid * 2048 + tid;
        #pragma unroll
        for (int i = 0; i < 8; i++) {
            int t = base + i * 256;
            const float* s; u16* d;
            if (t < 393216)      { s = x;  d = xb; }
            else if (t < 638976) { s = w1; d = w1b; t -= 393216; }
            else                 { s = w2; d = w2b; t -= 638976; }
            float4 v = ((const float4*)s)[t];
            ushort4 o;
            o.x = f2bf(v.x); o.y = f2bf(v.y); o.z = f2bf(v.z); o.w = f2bf(v.w);
            ((ushort4*)d)[t] = o;
        }
    }
    gridbar(bar, bid, 1);

    // ---- P1: qkv^T = w_qkv @ x^T, 640 tiles (20 dim x 32 pix).
    for (int t = bid; t < 640; t += GRID) {
        int bm = (t / 32) * 64, bn = (t % 32) * 64;
        gemm_tile<1>(w1b, xb, nullptr, qkvb, vTb, bm, bn, 768, sm.g);
    }
    gridbar(bar, bid, 2);

    // ---- P2: natten, 384 tiles (12 heads x 32 pixel-tiles).
    natten_tile(qkvb, vTb, ob, bid % 12, bid / 12, sm.n);
    gridbar(bar, bid, 3);

    // ---- P3: out^T = w_out @ o^T, 384 tiles (12 dim x 32 pix).
    {
        int bm = (bid / 32) * 64, bn = (bid % 32) * 64;
        gemm_tile<0>(w2b, ob, out, nullptr, nullptr, bm, bn, 768, sm.g);
    }
}

extern "C" void kernel_launch(void* const* d_in, const int* in_sizes, int n_in,
                              void* d_out, int out_size, void* d_ws, size_t ws_size,
                              hipStream_t stream)
{
    const float* x     = (const float*)d_in[0];   // (2048, 768)
    const float* w_qkv = (const float*)d_in[1];   // (1280, 768)
    const float* w_out = (const float*)d_in[2];   // (768, 768)
    float* out = (float*)d_out;                   // (2048, 768) fp32

    char* ws = (char*)d_ws;
    unsigned* bar = (unsigned*)ws; ws += 512;                 // 8 shard counters
    u16* qkvb = (u16*)ws; ws += (size_t)2048 * 1024 * 2;      // q|k bf16, 4 MB
    u16* vTb  = (u16*)ws; ws += (size_t)256 * 2048 * 2 + 64;  // v^T bf16, 1 MB
    u16* xb   = (u16*)ws; ws += (size_t)2048 * 768 * 2;       // 3 MB
    u16* w1b  = (u16*)ws; ws += (size_t)1280 * 768 * 2;       // 2 MB
    u16* w2b  = (u16*)ws; ws += (size_t)768 * 768 * 2;        // 1.1 MB
    u16* ob   = (u16*)ws;                                     // 3 MB

    (void)hipMemsetAsync(bar, 0, 512, stream);  // zero barrier shards (capturable)
    mega_kernel<<<dim3(GRID), dim3(256), 0, stream>>>(
        x, w_qkv, w_out, xb, w1b, w2b, qkvb, vTb, ob, out, bar);
}

// Round 12
// 104.620 us; speedup vs baseline: 1.6915x; 1.6915x over previous
//
#include <hip/hip_runtime.h>
#include <hip/hip_bf16.h>

// ---------------------------------------------------------------------------
// NattenBlock: qkv GEMM -> 7x7 NATTEN (GQA 12q/4kv, D=64) -> out GEMM.
// 2048 pixels (2x32x32), d_model 768.
// Round 12: R9 structure (4 dispatches; persistent-kernel path closed — grid
// barrier costs ~30us on MI355X regardless of implementation, R11 measured).
// GEMM K-loop: BK 128 -> 256 (3 iters, half the exposed barrier drains,
// 32 MFMA/wave/iter to amortize each; 64 KB LDS, 2 blocks/CU).
// Natten: staging-free MFMA (R9). Convert: separate kernel (R6/R8 proved
// inline conversion loses).
// ---------------------------------------------------------------------------

typedef __attribute__((ext_vector_type(8))) __bf16 bf16x8;
typedef __attribute__((ext_vector_type(4))) float floatx4;
typedef unsigned short u16;

__device__ inline u16 f2bf(float f) {
    union { float f; unsigned u; } v; v.f = f;
    return (u16)((v.u + 0x7fff + ((v.u >> 16) & 1)) >> 16);   // RNE
}

__device__ inline void gl_lds16(const void* g, void* l) {
    __builtin_amdgcn_global_load_lds(
        (const __attribute__((address_space(1))) void*)g,
        (__attribute__((address_space(3))) void*)l, 16, 0, 0);
}

// fp32 -> bf16 for x (393216 f4), w_qkv (245760 f4), w_out (147456 f4).
__global__ __launch_bounds__(256) void convert_kernel(
    const float* __restrict__ x, const float* __restrict__ w1,
    const float* __restrict__ w2, u16* __restrict__ xb,
    u16* __restrict__ w1b, u16* __restrict__ w2b)
{
    int t = blockIdx.x * blockDim.x + threadIdx.x;   // 0..786431
    const float* s; u16* d;
    if (t < 393216)      { s = x;  d = xb; }
    else if (t < 638976) { s = w1; d = w1b; t -= 393216; }
    else                 { s = w2; d = w2b; t -= 638976; }
    float4 v = ((const float4*)s)[t];
    ushort4 o;
    o.x = f2bf(v.x); o.y = f2bf(v.y); o.z = f2bf(v.z); o.w = f2bf(v.w);
    ((ushort4*)d)[t] = o;
}

// Flipped GEMM-NT: C'[dim,pix] = A[dim,K] @ B[pix,K]^T, bf16 in, fp32 acc.
// 64x64 tile, BK=256 as 8 kc sub-tiles of [64][32] (m97 layout), glds
// staging: waves 0,1 stage A (16 chunks of 1KB each), waves 2,3 stage B.
// 3 K-iterations (K=768). 64 KB LDS -> 2 blocks/CU.
// MODE 1 (qkv): dim<1024 -> qkvb[pix*1024+dim] (ushort4); dim>=1024 ->
//   vT[(dim-1024)*2048+pix]. MODE 0 (out): out[pix*768+dim] float4.
template<int MODE>
__global__ __launch_bounds__(256) void gemm_nt(
    const u16* __restrict__ A, const u16* __restrict__ B,
    float* __restrict__ out, u16* __restrict__ Cq, u16* __restrict__ vT,
    int K)
{
    __shared__ __align__(16) u16 As[8 * 2048];   // 32 KB [kc][row][32]
    __shared__ __align__(16) u16 Bs[8 * 2048];   // 32 KB
    const int tid = threadIdx.x;
    const int lane = tid & 63;
    const int wave = tid >> 6;
    const int bm = blockIdx.y * 64;   // dim tile (A rows)
    const int bn = blockIdx.x * 64;   // pixel tile (B rows)
    const int qr = (wave >> 1) * 32;
    const int qc = (wave & 1) * 32;

    floatx4 acc[2][2] = {};

    const u16* Xsrc = (wave < 2) ? A : B;
    const int   bx  = (wave < 2) ? bm : bn;
    u16* Xlds       = (wave < 2) ? As : Bs;
    const int half  = wave & 1;
    const int l2 = lane >> 2;            // row within 16-row group
    const int l3 = (lane & 3) * 8;       // k-oct within 32
    int gofs[16], lofs[16];
    #pragma unroll
    for (int cc = 0; cc < 16; cc++) {
        int c = half * 16 + cc, kc = c & 7, rg = c >> 3;
        gofs[cc] = (bx + rg * 16 + l2) * K + kc * 32 + l3;
        lofs[cc] = kc * 2048 + rg * 512;
    }

    const int fr = lane & 15;
    const int fk = (lane >> 4) * 8;

    for (int k0 = 0; k0 < K; k0 += 256) {
        #pragma unroll
        for (int cc = 0; cc < 16; cc++)
            gl_lds16(Xsrc + gofs[cc] + k0, Xlds + lofs[cc]);
        __syncthreads();
        #pragma unroll
        for (int kc = 0; kc < 8; kc++) {
            bf16x8 af0 = *(const bf16x8*)&As[kc * 2048 + (qr +      fr) * 32 + fk];
            bf16x8 af1 = *(const bf16x8*)&As[kc * 2048 + (qr + 16 + fr) * 32 + fk];
            bf16x8 bf0 = *(const bf16x8*)&Bs[kc * 2048 + (qc +      fr) * 32 + fk];
            bf16x8 bf1 = *(const bf16x8*)&Bs[kc * 2048 + (qc + 16 + fr) * 32 + fk];
            acc[0][0] = __builtin_amdgcn_mfma_f32_16x16x32_bf16(af0, bf0, acc[0][0], 0, 0, 0);
            acc[0][1] = __builtin_amdgcn_mfma_f32_16x16x32_bf16(af0, bf1, acc[0][1], 0, 0, 0);
            acc[1][0] = __builtin_amdgcn_mfma_f32_16x16x32_bf16(af1, bf0, acc[1][0], 0, 0, 0);
            acc[1][1] = __builtin_amdgcn_mfma_f32_16x16x32_bf16(af1, bf1, acc[1][1], 0, 0, 0);
        }
        __syncthreads();
    }

    // C/D layout: col(=pixel) = lane&15, row(=dim) = (lane>>4)*4 + r.
    const int cr = (lane >> 4) * 4;
    const int ccol = lane & 15;
    #pragma unroll
    for (int i = 0; i < 2; i++) {
        #pragma unroll
        for (int j = 0; j < 2; j++) {
            const int row0 = bm + qr + i * 16 + cr;       // dim
            const int col  = bn + qc + j * 16 + ccol;     // pixel
            if (MODE == 0) {
                float4 w = {acc[i][j][0], acc[i][j][1], acc[i][j][2], acc[i][j][3]};
                *(float4*)&out[(size_t)col * 768 + row0] = w;
            } else {
                if (row0 < 1024) {
                    ushort4 w;
                    w.x = f2bf(acc[i][j][0]); w.y = f2bf(acc[i][j][1]);
                    w.z = f2bf(acc[i][j][2]); w.w = f2bf(acc[i][j][3]);
                    *(ushort4*)&Cq[(size_t)col * 1024 + row0] = w;
                } else {
                    #pragma unroll
                    for (int r = 0; r < 4; r++)
                        vT[(size_t)(row0 + r - 1024) * 2048 + col] = f2bf(acc[i][j][r]);
                }
            }
        }
    }
}

// NATTEN 7x7 MFMA, zero staging (R9). Block = (q-head h, 8x8 pixel tile),
// 4 waves x 16 queries. Rows wu_i..wu_i+13 (wu_i = clip(ti-3,0,18)), cols
// oj..oj+15 (oj = clip4(tj-3) in {0,4,12,16}) cover every query's window.
__global__ __launch_bounds__(256) void natten_mfma(
    const u16* __restrict__ qkv, const u16* __restrict__ vT,
    u16* __restrict__ o)
{
    __shared__ __align__(16) u16 Pw[4 * 512];   // 4 KB, per-wave P^T chunks
    const int h  = blockIdx.x;        // 0..11
    const int tb = blockIdx.y;        // 0..31
    const int g  = h & 3;             // kv head
    const int batch = tb >> 4;
    const int ti = ((tb >> 2) & 3) * 8;
    const int tj = (tb & 3) * 8;
    const int wu_i = min(max(ti - 3, 0), 18);
    const int oj   = min(max(tj - 3, 0) & ~3, 16);
    const int lane = threadIdx.x & 63, wave = threadIdx.x >> 6;
    const int pixbase = batch << 10;

    const int fr = lane & 15;
    const int fk = (lane >> 4) * 8;   // 0,8,16,24

    bf16x8 aq0, aq1;
    {
        int qq = wave * 16 + fr;
        int pixq = pixbase + (ti + (qq >> 3)) * 32 + tj + (qq & 7);
        const u16* qp = &qkv[(size_t)pixq * 1024 + h * 64];
        aq0 = *(const bf16x8*)(qp + fk);
        aq1 = *(const bf16x8*)(qp + 32 + fk);
    }

    bool colok[4]; int tlo[4], thi[4];
    #pragma unroll
    for (int r = 0; r < 4; r++) {
        int qq = wave * 16 + (lane >> 4) * 4 + r;
        int qi = ti + (qq >> 3), qj = tj + (qq & 7);
        int si = min(max(qi - 3, 0), 25);
        int sj = min(max(qj - 3, 0), 25);
        colok[r] = (oj + fr >= sj) && (oj + fr <= sj + 6);
        tlo[r] = si - wu_i; thi[r] = tlo[r] + 6;
    }

    float s[14][4];
    float mx[4] = {-1e30f, -1e30f, -1e30f, -1e30f};
    #pragma unroll
    for (int t = 0; t < 14; t++) {
        int kp = pixbase + (wu_i + t) * 32 + oj + fr;
        const u16* krow = &qkv[(size_t)kp * 1024 + 768 + g * 64];
        bf16x8 bk0 = *(const bf16x8*)(krow + fk);
        bf16x8 bk1 = *(const bf16x8*)(krow + 32 + fk);
        floatx4 a4 = {};
        a4 = __builtin_amdgcn_mfma_f32_16x16x32_bf16(aq0, bk0, a4, 0, 0, 0);
        a4 = __builtin_amdgcn_mfma_f32_16x16x32_bf16(aq1, bk1, a4, 0, 0, 0);
        #pragma unroll
        for (int r = 0; r < 4; r++) {
            bool v = colok[r] && (t >= tlo[r]) && (t <= thi[r]);
            s[t][r] = v ? a4[r] * 0.125f : -1e30f;
            mx[r] = fmaxf(mx[r], s[t][r]);
        }
    }
    #pragma unroll
    for (int r = 0; r < 4; r++) {
        mx[r] = fmaxf(mx[r], __shfl_xor(mx[r], 1));
        mx[r] = fmaxf(mx[r], __shfl_xor(mx[r], 2));
        mx[r] = fmaxf(mx[r], __shfl_xor(mx[r], 4));
        mx[r] = fmaxf(mx[r], __shfl_xor(mx[r], 8));
    }
    float l[4] = {0.f, 0.f, 0.f, 0.f};
    #pragma unroll
    for (int t = 0; t < 14; t++)
        #pragma unroll
        for (int r = 0; r < 4; r++) {
            float p = __expf(s[t][r] - mx[r]);
            s[t][r] = p; l[r] += p;
        }
    #pragma unroll
    for (int r = 0; r < 4; r++) {
        l[r] += __shfl_xor(l[r], 1);
        l[r] += __shfl_xor(l[r], 2);
        l[r] += __shfl_xor(l[r], 4);
        l[r] += __shfl_xor(l[r], 8);
    }
    float rinv[4];
    #pragma unroll
    for (int r = 0; r < 4; r++) rinv[r] = 1.0f / l[r];

    u16* pw = &Pw[wave * 512];
    floatx4 oacc[4] = {};
    const int vrow = (fk >= 16) ? 1 : 0;
    const int vcol = oj + (fk & 8);
    #pragma unroll
    for (int kc = 0; kc < 7; kc++) {
        #pragma unroll
        for (int tt = 0; tt < 2; tt++) {
            int t = kc * 2 + tt;
            #pragma unroll
            for (int r = 0; r < 4; r++)
                pw[((lane >> 4) * 4 + r) * 32 + tt * 16 + fr] =
                    f2bf(s[t][r] * rinv[r]);
        }
        bf16x8 bp = *(const bf16x8*)&pw[fr * 32 + fk];
        const int vpix = pixbase + (wu_i + kc * 2 + vrow) * 32 + vcol;
        #pragma unroll
        for (int u = 0; u < 4; u++) {
            const u16* vp = &vT[(size_t)(g * 64 + u * 16 + fr) * 2048 + vpix];
            union { ushort4 q[2]; bf16x8 v; } av;
            av.q[0] = *(const ushort4*)vp;
            av.q[1] = *(const ushort4*)(vp + 4);
            oacc[u] = __builtin_amdgcn_mfma_f32_16x16x32_bf16(av.v, bp, oacc[u], 0, 0, 0);
        }
    }

    {
        int qq = wave * 16 + fr;
        int pixq = pixbase + (ti + (qq >> 3)) * 32 + tj + (qq & 7);
        u16* op = &o[(size_t)pixq * 768 + h * 64];
        #pragma unroll
        for (int u = 0; u < 4; u++) {
            ushort4 w;
            w.x = f2bf(oacc[u][0]); w.y = f2bf(oacc[u][1]);
            w.z = f2bf(oacc[u][2]); w.w = f2bf(oacc[u][3]);
            *(ushort4*)(op + u * 16 + (lane >> 4) * 4) = w;
        }
    }
}

extern "C" void kernel_launch(void* const* d_in, const int* in_sizes, int n_in,
                              void* d_out, int out_size, void* d_ws, size_t ws_size,
                              hipStream_t stream)
{
    const float* x     = (const float*)d_in[0];   // (2048, 768)
    const float* w_qkv = (const float*)d_in[1];   // (1280, 768)
    const float* w_out = (const float*)d_in[2];   // (768, 768)
    float* out = (float*)d_out;                   // (2048, 768) fp32

    char* ws = (char*)d_ws;
    u16* qkvb = (u16*)ws; ws += (size_t)2048 * 1024 * 2;      // q|k bf16, 4 MB
    u16* vTb  = (u16*)ws; ws += (size_t)256 * 2048 * 2 + 64;  // v^T bf16, 1 MB
    u16* xb   = (u16*)ws; ws += (size_t)2048 * 768 * 2;       // 3 MB
    u16* w1b  = (u16*)ws; ws += (size_t)1280 * 768 * 2;       // 2 MB
    u16* w2b  = (u16*)ws; ws += (size_t)768 * 768 * 2;        // 1.1 MB
    u16* ob   = (u16*)ws;                                     // 3 MB

    convert_kernel<<<dim3(3072), dim3(256), 0, stream>>>(x, w_qkv, w_out, xb, w1b, w2b);

    // qkv^T = w_qkv @ x^T -> qkvb[pix][dim<1024] + vT[dim-1024][pix]
    gemm_nt<1><<<dim3(2048 / 64, 1280 / 64), dim3(256), 0, stream>>>(
        w1b, xb, nullptr, qkvb, vTb, 768);

    natten_mfma<<<dim3(12, 32), dim3(256), 0, stream>>>(qkvb, vTb, ob);

    // out^T = w_out @ o^T -> out[pix][dim] (float4 on dim axis)
    gemm_nt<0><<<dim3(2048 / 64, 768 / 64), dim3(256), 0, stream>>>(
        w2b, ob, out, nullptr, nullptr, 768);
}